// Round 1
// 360.579 us; speedup vs baseline: 1.0738x; 1.0738x over previous
//
#include <hip/hip_runtime.h>
#include <cstdint>

typedef _Float16 half8 __attribute__((ext_vector_type(8)));
typedef __attribute__((ext_vector_type(4))) float floatx4;

#define TSEQ 256
#define TDEC 180
#define NIN  6
#define GROWS 16
#define NBLK (4096 / GROWS)
#define NSL 4     // state buffer depth: h(j) lives in slot (j+1)&3
#define RS0 104   // s0 row stride (halfs): cols 0..63 h0, 64..95 x|0, 96..103 pad
#define RS1 72    // s1 row stride
#define L2E 1.4426950408889634f

__device__ __forceinline__ floatx4 mfma16(half8 a, half8 b, floatx4 c) {
  return __builtin_amdgcn_mfma_f32_16x16x32_f16(a, b, c, 0, 0, 0);
}

// pre-scaled transcendentals: inputs already carry log2e (sigm) / 2*log2e (tanh)
__device__ __forceinline__ float sigm2(float v) {
  return __builtin_amdgcn_rcpf(1.0f + __builtin_amdgcn_exp2f(-v));
}
__device__ __forceinline__ float tanh2(float v) {
  return fmaf(2.0f, __builtin_amdgcn_rcpf(1.0f + __builtin_amdgcn_exp2f(-v)), -1.0f);
}

__device__ __forceinline__ half8 ldh8(const _Float16* p) { return *(const half8*)p; }

#define PASS2_I3(F0, F1, r, z, g, W, QR, QZ, QG) do {                   \
  r = mfma16(F0, W[0][0], QR); z = mfma16(F0, W[1][0], QZ); g = mfma16(F0, W[2][0], QG); \
  r = mfma16(F1, W[0][1], r);  z = mfma16(F1, W[1][1], z);  g = mfma16(F1, W[2][1], g);  \
} while (0)

#define PASS2_A2I1(F0, F1, r, z, g, W, QG) do {                         \
  r = mfma16(F0, W[0][0], r); z = mfma16(F0, W[1][0], z); g = mfma16(F0, W[2][0], QG); \
  r = mfma16(F1, W[0][1], r); z = mfma16(F1, W[1][1], z); g = mfma16(F1, W[2][1], g);  \
} while (0)

#define PASS1_A2I1(F0, r, z, g, W, QG) do {                             \
  r = mfma16(F0, W[0][0], r); z = mfma16(F0, W[1][0], z); g = mfma16(F0, W[2][0], QG); \
} while (0)

// Lockstep barrier: drain this wave's LDS ops (writes become visible), then
// raw s_barrier. Deliberately NO vmcnt drain so the x global prefetch loads
// stay in flight across barriers. Memory clobbers pin LDS ops on each side.
#define SYNC() do {                                         \
  asm volatile("s_waitcnt lgkmcnt(0)" ::: "memory");        \
  __builtin_amdgcn_s_barrier();                             \
  asm volatile("" ::: "memory");                            \
} while (0)

__global__ void __launch_bounds__(512, 2)
gru_persist(const float* __restrict__ x,
            const float* __restrict__ eWih0, const float* __restrict__ eWhh0,
            const float* __restrict__ ebih0, const float* __restrict__ ebhh0,
            const float* __restrict__ eWih1, const float* __restrict__ eWhh1,
            const float* __restrict__ ebih1, const float* __restrict__ ebhh1,
            const float* __restrict__ dWih0, const float* __restrict__ dWhh0,
            const float* __restrict__ dbih0, const float* __restrict__ dbhh0,
            const float* __restrict__ dWih1, const float* __restrict__ dWhh1,
            const float* __restrict__ dbih1, const float* __restrict__ dbhh1,
            const float* __restrict__ outW, const float* __restrict__ outB,
            float* __restrict__ out)
{
  __shared__ __align__(16) _Float16 s0[NSL][16][RS0];
  __shared__ __align__(16) _Float16 s1[NSL][16][RS1];

  const int tid  = threadIdx.x;
  const bool isA = tid < 256;          // A = layer0 waves, B = layer1 waves
  const int wvL  = (tid >> 6) & 3;
  const int lane = tid & 63;
  const int c    = lane & 15;
  const int q    = lane >> 4;
  const int u    = wvL * 16 + c;
  const long base = (long)blockIdx.x * GROWS;

  for (int i = tid; i < NSL * 16 * RS0; i += 512) ((uint16_t*)s0)[i] = 0;
  for (int i = tid; i < NSL * 16 * RS1; i += 512) ((uint16_t*)s1)[i] = 0;
  if (tid < GROWS * NIN) {  // x(0) -> s0[0]
    int m = tid / 6, i2 = tid - m * 6;
    s0[0][m][64 + i2] = (_Float16)x[(base + m) * (TSEQ * NIN) + i2];
  }

  // encoder + decoder weights ALL register-resident from the start (no mid-kernel loads)
  half8 W1[3][2], W2[3][2];    // encoder: A: Whh0 / [Wih0|0] | B: Wih1 / Whh1
  half8 W1d[3][2], W2d[3][2];  // decoder: A: Whh0d / rank-1 fold | B: Wih1d / Whh1d
  float hr[4] = {0, 0, 0, 0};
  const float SC[3] = {L2E, L2E, 2.0f * L2E};   // r, z, n row scales (fold exp2 args)

  auto loadW64 = [&](const float* W, half8 (&D)[3][2]) {
    #pragma unroll
    for (int s = 0; s < 3; s++) {
      const int n = (s * 4 + wvL) * 16 + c;
      #pragma unroll
      for (int kt = 0; kt < 2; kt++) {
        const int k0 = kt * 32 + q * 8;
        #pragma unroll
        for (int j = 0; j < 8; j++) D[s][kt][j] = (_Float16)(SC[s] * W[n * 64 + k0 + j]);
      }
    }
  };

  const float ob = outB[0];
  float cR, cZ, c3, c4;          // encoder consts
  float dR, dZ, d3, d4;          // decoder steady consts
  float bR0 = 0, bZ0 = 0, b30 = 0, b40 = 0;   // A decoder first-step consts
  float wk[2][8];                // B: head weights
  if (isA) {
    loadW64(eWhh0, W1);
    #pragma unroll
    for (int s = 0; s < 3; s++) {
      const int n = (s * 4 + wvL) * 16 + c;
      #pragma unroll
      for (int kt = 0; kt < 2; kt++)
        #pragma unroll
        for (int j = 0; j < 8; j++) {
          float v = (kt == 0 && q == 0 && j < NIN) ? SC[s] * eWih0[n * NIN + j] : 0.0f;
          W2[s][kt][j] = (_Float16)v;
        }
    }
    loadW64(dWhh0, W1d);
    #pragma unroll
    for (int s = 0; s < 3; s++) {   // W2d = rank-1 head fold: SC[s] * dWih0[n] * outW[k]
      const int n = (s * 4 + wvL) * 16 + c;
      const float wd = SC[s] * dWih0[n];
      #pragma unroll
      for (int kt = 0; kt < 2; kt++) {
        const int k0 = kt * 32 + q * 8;
        #pragma unroll
        for (int j = 0; j < 8; j++) W2d[s][kt][j] = (_Float16)(wd * outW[k0 + j]);
      }
    }
    cR = L2E * (ebih0[u] + ebhh0[u]);
    cZ = L2E * (ebih0[64 + u] + ebhh0[64 + u]);
    c3 = 2.0f * L2E * ebhh0[128 + u];   // gh const
    c4 = 2.0f * L2E * ebih0[128 + u];   // gi const
    bR0 = L2E * (dbih0[u] + dbhh0[u]);
    bZ0 = L2E * (dbih0[64 + u] + dbhh0[64 + u]);
    b30 = 2.0f * L2E * dbhh0[128 + u];
    b40 = 2.0f * L2E * dbih0[128 + u];
    dR = bR0 + L2E * (dWih0[u] * ob);
    dZ = bZ0 + L2E * (dWih0[64 + u] * ob);
    d3 = b30;
    d4 = b40 + 2.0f * L2E * (dWih0[128 + u] * ob);
  } else {
    loadW64(eWih1, W1); loadW64(eWhh1, W2);
    loadW64(dWih1, W1d); loadW64(dWhh1, W2d);
    cR = L2E * (ebih1[u] + ebhh1[u]);
    cZ = L2E * (ebih1[64 + u] + ebhh1[64 + u]);
    c3 = 2.0f * L2E * ebih1[128 + u];   // gi const
    c4 = 2.0f * L2E * ebhh1[128 + u];   // gh const
    dR = L2E * (dbih1[u] + dbhh1[u]);
    dZ = L2E * (dbih1[64 + u] + dbhh1[64 + u]);
    d3 = 2.0f * L2E * dbih1[128 + u];
    d4 = 2.0f * L2E * dbhh1[128 + u];
    #pragma unroll
    for (int kt = 0; kt < 2; kt++)
      #pragma unroll
      for (int j = 0; j < 8; j++) wk[kt][j] = outW[kt * 32 + q * 8 + j];
  }
  __syncthreads();   // everything after runs on the lockstep barrier schedule

  // Barrier schedule (both sides execute exactly 616 SYNCs):
  //   encoder: 256 iters (1 SYNC each) + 1 tail iter (A: decoder peel, B: enc step 255)
  //   decoder: B(0) window (1 SYNC), then 179 iters x 2 SYNCs; A adds 1 trailing SYNC.
  if (isA) {
    floatx4 QR = {cR, cR, cR, cR}, QZ = {cZ, cZ, cZ, cZ};
    floatx4 Q3 = {c3, c3, c3, c3}, Q4 = {c4, c4, c4, c4};
    // ---- x prefetch, wave A0, lanes 0..47, 2 slots each, depth 2 ----
    const bool doX = (wvL == 0) && (lane < 48);
    const float *px0 = nullptr, *px1 = nullptr;
    int xo0 = 0, xo1 = 0;
    float xa0 = 0.f, xa1 = 0.f, xb0 = 0.f, xb1 = 0.f;   // (xa=next-to-write, xb=following)
    if (doX) {
      int s0_ = lane, s1_ = lane + 48;
      int m0 = s0_ / 6, i0 = s0_ - m0 * 6, m1 = s1_ / 6, i1 = s1_ - m1 * 6;
      px0 = x + (base + m0) * (TSEQ * NIN) + i0;
      px1 = x + (base + m1) * (TSEQ * NIN) + i1;
      xo0 = m0 * RS0 + 64 + i0; xo1 = m1 * RS0 + 64 + i1;
      xa0 = px0[NIN];     xa1 = px1[NIN];       // x(1)
      xb0 = px0[2 * NIN]; xb1 = px1[2 * NIN];   // x(2)
    }
    // ================= encoder: iteration k computes h0_out(k) =================
    for (int k = 0; k < TSEQ; k += 4) {
      #pragma unroll
      for (int h4 = 0; h4 < 4; h4++) {
        const int i_ = k + h4, p = h4, pn = (h4 + 1) & 3;
        const half8 a0 = ldh8(&s0[p][c][q * 8]);
        const half8 a1 = ldh8(&s0[p][c][32 + q * 8]);
        const half8 xf = ldh8(&s0[p][c][64 + q * 8]);
        floatx4 aR, aZ, a3, a4;
        PASS2_I3(a0, a1, aR, aZ, a3, W1, QR, QZ, Q3);  // Whh0.h0 -> gh
        PASS1_A2I1(xf, aR, aZ, a4, W2, Q4);            // Wih0.x  -> gi
        if (doX && i_ + 1 < TSEQ) {
          ((_Float16*)s0[pn])[xo0] = (_Float16)xa0;
          ((_Float16*)s0[pn])[xo1] = (_Float16)xa1;
          xa0 = xb0; xa1 = xb1;
          if (i_ + 3 < TSEQ) { xb0 = px0[(i_ + 3) * NIN]; xb1 = px1[(i_ + 3) * NIN]; }
        }
        #pragma unroll
        for (int r4 = 0; r4 < 4; r4++) {
          const float gr = sigm2(aR[r4]);
          const float gz = sigm2(aZ[r4]);
          const float nn = tanh2(a4[r4] + gr * a3[r4]);
          const float hn = nn + gz * (hr[r4] - nn);
          hr[r4] = hn;
          s0[pn][q * 4 + r4][u] = (_Float16)hn;
        }
        SYNC();
      }
    }
    // ---- tail iteration (k=TSEQ): decoder peel A(0), prev = 0 -> base biases ----
    // s0[0] = h0_out(255); writes h0_dec(0) -> s0[1]. Overlaps B's enc step 255.
    {
      const half8 a0 = ldh8(&s0[0][c][q * 8]);
      const half8 a1 = ldh8(&s0[0][c][32 + q * 8]);
      const floatx4 TR = {bR0, bR0, bR0, bR0}, TZ = {bZ0, bZ0, bZ0, bZ0};
      const floatx4 T3 = {b30, b30, b30, b30};
      floatx4 aR, aZ, a3;
      floatx4 a4 = {b40, b40, b40, b40};
      PASS2_I3(a0, a1, aR, aZ, a3, W1d, TR, TZ, T3);
      #pragma unroll
      for (int r4 = 0; r4 < 4; r4++) {
        const float gr = sigm2(aR[r4]);
        const float gz = sigm2(aZ[r4]);
        const float nn = tanh2(a4[r4] + gr * a3[r4]);
        const float hn = nn + gz * (hr[r4] - nn);
        hr[r4] = hn;
        s0[1][q * 4 + r4][u] = (_Float16)hn;
      }
      SYNC();   // bar0: h0_dec(0) visible; B(0) runs in the next window
    }
    // ---- decoder steady: d = 1..179 (i_ = TSEQ+d), 2 barriers per step ----
    QR = (floatx4){dR, dR, dR, dR}; QZ = (floatx4){dZ, dZ, dZ, dZ};
    Q3 = (floatx4){d3, d3, d3, d3}; Q4 = (floatx4){d4, d4, d4, d4};
    for (int i_ = TSEQ + 1; i_ < TSEQ + TDEC; i_++) {
      const int p = i_ & 3, pn = (i_ + 1) & 3;
      // prepass (overlaps B finishing d-1): Whh0d.h0_dec(d-1)
      const half8 a0 = ldh8(&s0[p][c][q * 8]);
      const half8 a1 = ldh8(&s0[p][c][32 + q * 8]);
      floatx4 aR, aZ, a3, a4;
      PASS2_I3(a0, a1, aR, aZ, a3, W1d, QR, QZ, Q3);
      SYNC();                                          // B(d-1) done -> s1[p] = h1(d-1)
      const half8 b0 = ldh8(&s1[p][c][q * 8]);         // rank-1 head fold: W'.h1(d-1)
      const half8 b1 = ldh8(&s1[p][c][32 + q * 8]);
      PASS2_A2I1(b0, b1, aR, aZ, a4, W2d, Q4);
      #pragma unroll
      for (int r4 = 0; r4 < 4; r4++) {
        const float gr = sigm2(aR[r4]);
        const float gz = sigm2(aZ[r4]);
        const float nn = tanh2(a4[r4] + gr * a3[r4]);
        const float hn = nn + gz * (hr[r4] - nn);
        hr[r4] = hn;
        s0[pn][q * 4 + r4][u] = (_Float16)hn;
      }
      SYNC();                                          // A(d) done -> s0[pn]
    }
    SYNC();   // match B's barrier after its last finish (B(179))
  } else {
    // =========================== group B: layer 1 ===========================
    floatx4 QR = {cR, cR, cR, cR}, QZ = {cZ, cZ, cZ, cZ};
    floatx4 Q3 = {c3, c3, c3, c3}, Q4 = {c4, c4, c4, c4};
    // ============ encoder: iteration kk computes h1_out(kk-1), kk>=1 ============
    for (int k = 0; k < TSEQ; k += 4) {
      #pragma unroll
      for (int h4 = 0; h4 < 4; h4++) {
        const int kk = k + h4;
        if (kk > 0) {
          const int p = (h4 + 3) & 3, pn = h4;         // read s1[(kk-1)&3], s0[kk&3]
          const half8 f0 = ldh8(&s1[p][c][q * 8]);
          const half8 f1 = ldh8(&s1[p][c][32 + q * 8]);
          floatx4 aR, aZ, a3, a4;
          PASS2_I3(f0, f1, aR, aZ, a4, W2, QR, QZ, Q4);  // Whh1.h1 -> gh
          const half8 g0 = ldh8(&s0[pn][c][q * 8]);      // h0_out(kk-1), from prev window
          const half8 g1 = ldh8(&s0[pn][c][32 + q * 8]);
          PASS2_A2I1(g0, g1, aR, aZ, a3, W1, Q3);        // Wih1.h0 -> gi
          #pragma unroll
          for (int r4 = 0; r4 < 4; r4++) {
            const float gr = sigm2(aR[r4]);
            const float gz = sigm2(aZ[r4]);
            const float nn = tanh2(a3[r4] + gr * a4[r4]);
            const float hn = nn + gz * (hr[r4] - nn);
            hr[r4] = hn;
            s1[pn][q * 4 + r4][u] = (_Float16)hn;
          }
        }
        SYNC();
      }
    }
    // ---- tail iteration (kk=TSEQ): encoder step i_=255: s1[3], s0[0] -> s1[0] ----
    {
      const half8 f0 = ldh8(&s1[3][c][q * 8]);
      const half8 f1 = ldh8(&s1[3][c][32 + q * 8]);
      floatx4 aR, aZ, a3, a4;
      PASS2_I3(f0, f1, aR, aZ, a4, W2, QR, QZ, Q4);
      const half8 g0 = ldh8(&s0[0][c][q * 8]);
      const half8 g1 = ldh8(&s0[0][c][32 + q * 8]);
      PASS2_A2I1(g0, g1, aR, aZ, a3, W1, Q3);
      #pragma unroll
      for (int r4 = 0; r4 < 4; r4++) {
        const float gr = sigm2(aR[r4]);
        const float gz = sigm2(aZ[r4]);
        const float nn = tanh2(a3[r4] + gr * a4[r4]);
        const float hn = nn + gz * (hr[r4] - nn);
        hr[r4] = hn;
        s1[0][q * 4 + r4][u] = (_Float16)hn;
      }
      SYNC();   // bar0
    }
    QR = (floatx4){dR, dR, dR, dR}; QZ = (floatx4){dZ, dZ, dZ, dZ};
    Q3 = (floatx4){d3, d3, d3, d3}; Q4 = (floatx4){d4, d4, d4, d4};
    // ---- B(0): s1[0] = h1_out(255), s0[1] = h0_dec(0) -> s1[1] = h1_dec(0) ----
    {
      const half8 f0 = ldh8(&s1[0][c][q * 8]);
      const half8 f1 = ldh8(&s1[0][c][32 + q * 8]);
      floatx4 aR, aZ, a3, a4;
      PASS2_I3(f0, f1, aR, aZ, a4, W2d, QR, QZ, Q4);
      const half8 g0 = ldh8(&s0[1][c][q * 8]);
      const half8 g1 = ldh8(&s0[1][c][32 + q * 8]);
      PASS2_A2I1(g0, g1, aR, aZ, a3, W1d, Q3);
      #pragma unroll
      for (int r4 = 0; r4 < 4; r4++) {
        const float gr = sigm2(aR[r4]);
        const float gz = sigm2(aZ[r4]);
        const float nn = tanh2(a3[r4] + gr * a4[r4]);
        const float hn = nn + gz * (hr[r4] - nn);
        hr[r4] = hn;
        s1[1][q * 4 + r4][u] = (_Float16)hn;
      }
      SYNC();   // bar1: h1_dec(0) visible
    }
    // ---- decoder steady: d = 1..179 (i_ = TSEQ+d), 2 barriers per step ----
    for (int i_ = TSEQ + 1; i_ < TSEQ + TDEC; i_++) {
      const int p = i_ & 3, pn = (i_ + 1) & 3;
      // prepass (overlaps A finishing d): Whh1d.h1_dec(d-1), + head cv(d-1)
      const half8 f0 = ldh8(&s1[p][c][q * 8]);
      const half8 f1 = ldh8(&s1[p][c][32 + q * 8]);
      floatx4 aR, aZ, a3, a4;
      PASS2_I3(f0, f1, aR, aZ, a4, W2d, QR, QZ, Q4);   // Whh1.h1 -> gh
      if (wvL == 0) {   // head: cv(d-1) from h1_dec(d-1) fragments (off critical path)
        float cv = 0.0f;
        #pragma unroll
        for (int j = 0; j < 8; j++) {
          cv = fmaf((float)f0[j], wk[0][j], cv);
          cv = fmaf((float)f1[j], wk[1][j], cv);
        }
        cv += __shfl_xor(cv, 16);
        cv += __shfl_xor(cv, 32);
        if (lane < 16) out[(base + lane) * TDEC + (i_ - TSEQ - 1)] = cv + ob;
      }
      SYNC();                                          // A(d) done -> s0[pn] = h0_dec(d)
      const half8 g0 = ldh8(&s0[pn][c][q * 8]);
      const half8 g1 = ldh8(&s0[pn][c][32 + q * 8]);
      PASS2_A2I1(g0, g1, aR, aZ, a3, W1d, Q3);         // Wih1.h0 -> gi
      #pragma unroll
      for (int r4 = 0; r4 < 4; r4++) {
        const float gr = sigm2(aR[r4]);
        const float gz = sigm2(aZ[r4]);
        const float nn = tanh2(a3[r4] + gr * a4[r4]);
        const float hn = nn + gz * (hr[r4] - nn);
        hr[r4] = hn;
        s1[pn][q * 4 + r4][u] = (_Float16)hn;
      }
      SYNC();                                          // B(d) done -> s1[pn]
    }
    // final head value: cv(179) from h1_dec(179) in s1[(436)&3 = 0]
    if (wvL == 0) {
      const half8 f0 = ldh8(&s1[0][c][q * 8]);
      const half8 f1 = ldh8(&s1[0][c][32 + q * 8]);
      float cv = 0.0f;
      #pragma unroll
      for (int j = 0; j < 8; j++) {
        cv = fmaf((float)f0[j], wk[0][j], cv);
        cv = fmaf((float)f1[j], wk[1][j], cv);
      }
      cv += __shfl_xor(cv, 16);
      cv += __shfl_xor(cv, 32);
      if (lane < 16) out[(base + lane) * TDEC + (TDEC - 1)] = cv + ob;
    }
  }
}

extern "C" void kernel_launch(void* const* d_in, const int* in_sizes, int n_in,
                              void* d_out, int out_size, void* d_ws, size_t ws_size,
                              hipStream_t stream) {
  (void)in_sizes; (void)n_in; (void)d_ws; (void)ws_size; (void)out_size;
  const float* x     = (const float*)d_in[0];
  const float* eWih0 = (const float*)d_in[1];
  const float* eWhh0 = (const float*)d_in[2];
  const float* ebih0 = (const float*)d_in[3];
  const float* ebhh0 = (const float*)d_in[4];
  const float* eWih1 = (const float*)d_in[5];
  const float* eWhh1 = (const float*)d_in[6];
  const float* ebih1 = (const float*)d_in[7];
  const float* ebhh1 = (const float*)d_in[8];
  const float* dWih0 = (const float*)d_in[9];
  const float* dWhh0 = (const float*)d_in[10];
  const float* dbih0 = (const float*)d_in[11];
  const float* dbhh0 = (const float*)d_in[12];
  const float* dWih1 = (const float*)d_in[13];
  const float* dWhh1 = (const float*)d_in[14];
  const float* dbih1 = (const float*)d_in[15];
  const float* dbhh1 = (const float*)d_in[16];
  const float* outW  = (const float*)d_in[17];
  const float* outB  = (const float*)d_in[18];
  hipLaunchKernelGGL(gru_persist, dim3(NBLK), dim3(512), 0, stream,
                     x, eWih0, eWhh0, ebih0, ebhh0, eWih1, eWhh1, ebih1, ebhh1,
                     dWih0, dWhh0, dbih0, dbhh0, dWih1, dWhh1, dbih1, dbhh1,
                     outW, outB, (float*)d_out);
}